// Round 5
// baseline (1309.181 us; speedup 1.0000x reference)
//
#include <hip/hip_runtime.h>
#include <math.h>

#define C_DIM 1024
#define T_DIM 2048
#define B_DIM 2
#define H_NUM 16
#define M_TOK (B_DIM * T_DIM)

typedef _Float16 f16x8 __attribute__((ext_vector_type(8)));
typedef _Float16 f16x4 __attribute__((ext_vector_type(4)));
typedef float f32x4 __attribute__((ext_vector_type(4)));

// async global->LDS, 16B per lane; dest is wave-uniform base + lane*16 (linear).
#define GLD16(g, l) __builtin_amdgcn_global_load_lds(                          \
    (const __attribute__((address_space(1))) void*)(g),                        \
    (__attribute__((address_space(3))) void*)(l), 16, 0, 0)

__device__ __forceinline__ float gelu_f(float v) {
    return 0.5f * v * (1.0f + erff(v * 0.70710678118654752440f));
}

// ---------------- LayerNorm -> split fp16 pair (optionally fused residual) ----
// grid = M_TOK blocks, 256 threads; each thread owns one float4 of the row.
__global__ __launch_bounds__(256)
void ln_split_kernel(const float* __restrict__ xin, const float* __restrict__ yadd,
                     const float* __restrict__ gw, const float* __restrict__ bw,
                     _Float16* __restrict__ hh, _Float16* __restrict__ hl,
                     float* __restrict__ xout)
{
    const int row = blockIdx.x;
    const int t = threadIdx.x;
    const size_t off = (size_t)row * C_DIM;
    float4 v = reinterpret_cast<const float4*>(xin + off)[t];
    if (yadd != nullptr) {
        float4 w = reinterpret_cast<const float4*>(yadd + off)[t];
        v.x += w.x; v.y += w.y; v.z += w.z; v.w += w.w;
        reinterpret_cast<float4*>(xout + off)[t] = v;
    }
    float s1 = v.x + v.y + v.z + v.w;
    float s2 = v.x * v.x + v.y * v.y + v.z * v.z + v.w * v.w;
#pragma unroll
    for (int m = 1; m < 64; m <<= 1) {
        s1 += __shfl_xor(s1, m);
        s2 += __shfl_xor(s2, m);
    }
    __shared__ float r1[4], r2[4];
    if ((t & 63) == 0) { r1[t >> 6] = s1; r2[t >> 6] = s2; }
    __syncthreads();
    s1 = r1[0] + r1[1] + r1[2] + r1[3];
    s2 = r2[0] + r2[1] + r2[2] + r2[3];
    const float mean = s1 * (1.0f / C_DIM);
    const float var = s2 * (1.0f / C_DIM) - mean * mean;
    const float rstd = rsqrtf(var + 1e-5f);
    const float4 g4 = reinterpret_cast<const float4*>(gw)[t];
    const float4 b4 = reinterpret_cast<const float4*>(bw)[t];
    float o0 = (v.x - mean) * rstd * g4.x + b4.x;
    float o1 = (v.y - mean) * rstd * g4.y + b4.y;
    float o2 = (v.z - mean) * rstd * g4.z + b4.z;
    float o3 = (v.w - mean) * rstd * g4.w + b4.w;
    f16x4 vh, vl;
    vh[0] = (_Float16)o0; vh[1] = (_Float16)o1; vh[2] = (_Float16)o2; vh[3] = (_Float16)o3;
    vl[0] = (_Float16)((o0 - (float)vh[0]) * 2048.0f);
    vl[1] = (_Float16)((o1 - (float)vh[1]) * 2048.0f);
    vl[2] = (_Float16)((o2 - (float)vh[2]) * 2048.0f);
    vl[3] = (_Float16)((o3 - (float)vh[3]) * 2048.0f);
    reinterpret_cast<f16x4*>(hh + off)[t] = vh;
    reinterpret_cast<f16x4*>(hl + off)[t] = vl;
}

// ---------------- weight transpose + split: W[K,N] fp32 -> Wt_h/Wt_l [N,K] fp16 ----
// grid = (N/32, K/32), 256 threads.
__global__ __launch_bounds__(256)
void wsplit_kernel(const float* __restrict__ W, _Float16* __restrict__ Wth,
                   _Float16* __restrict__ Wtl, int K, int N)
{
    __shared__ float tile[32][33];
    const int bx = blockIdx.x;   // tile along N
    const int by = blockIdx.y;   // tile along K
    const int t = threadIdx.x;
    const int c = t & 31;
    const int r4 = (t >> 5) * 4;
#pragma unroll
    for (int i = 0; i < 4; ++i)
        tile[r4 + i][c] = W[(size_t)(by * 32 + r4 + i) * N + bx * 32 + c];
    __syncthreads();
#pragma unroll
    for (int i = 0; i < 4; ++i) {
        const float v = tile[c][r4 + i];          // = W[by*32+c][bx*32+r4+i]
        const int nn = bx * 32 + r4 + i;          // out row (N)
        const int kk = by * 32 + c;               // out col (K)
        const _Float16 hi = (_Float16)v;
        const _Float16 lo = (_Float16)((v - (float)hi) * 2048.0f);
        Wth[(size_t)nn * K + kk] = hi;
        Wtl[(size_t)nn * K + kk] = lo;
    }
}

// ---------------- fp16x2 split MFMA GEMM (global_load_lds staging) ----------------
// C = A[M,K] @ B[K,N] + bias, computed as Ah.Bh + 2^-11 (Al.Bh + Ah.Bl).
// A given as split pair [M,K]; B given TRANSPOSED split pair Bt[N,K].
// 64(M) x 128(N) tile, BK=32, 256 threads = 4 waves (2m x 2n), wave tile 32x64.
// mfma_f32_16x16x32_f16: A-frag row=l&15,k=(l>>4)*8+j ; C/D row=(l>>4)*4+r, col=l&15.
#define BTM 64
#define BTN 128
#define BK 32

template <int EPI>   // 0: fp32 out +bias | 1: gelu -> split fp16 out | 2: fp32 out +bias+resid
__global__ __launch_bounds__(256, 3)
void gemm16_kernel(const _Float16* __restrict__ Ah, const _Float16* __restrict__ Al,
                   const _Float16* __restrict__ Bth, const _Float16* __restrict__ Btl,
                   const float* __restrict__ bias, const float* __restrict__ resid,
                   float* __restrict__ Co, _Float16* __restrict__ Oh, _Float16* __restrict__ Ol,
                   int M, int N, int K)
{
    __shared__ __align__(16) _Float16 As_h[BTM * BK];   // 4 KB
    __shared__ __align__(16) _Float16 As_l[BTM * BK];   // 4 KB
    __shared__ __align__(16) _Float16 Bs_h[BTN * BK];   // 8 KB
    __shared__ __align__(16) _Float16 Bs_l[BTN * BK];   // 8 KB

    const int t = threadIdx.x;
    const int l = t & 63;
    const int w = t >> 6;         // 0..3
    const int wm = w >> 1;        // 0..1 : 32-row block
    const int wn = w & 1;         // 0..1 : 64-col block
    const int bm = blockIdx.y * BTM;
    const int bn = blockIdx.x * BTN;

    // staging: chunk c -> LDS bytes [c*16, c*16+16), global row = c>>2, koff = (c&3)*8.
    // A: chunks 0..255 (c = t). B: chunks 0..511 (c = t and t+256).
    const int crow = t >> 2;
    const int ckoff = (t & 3) * 8;
    const _Float16* ApH  = Ah  + (size_t)(bm + crow) * K + ckoff;
    const _Float16* ApL  = Al  + (size_t)(bm + crow) * K + ckoff;
    const _Float16* BpH  = Bth + (size_t)(bn + crow) * K + ckoff;
    const _Float16* BpL  = Btl + (size_t)(bn + crow) * K + ckoff;
    const _Float16* BpH2 = BpH + (size_t)64 * K;
    const _Float16* BpL2 = BpL + (size_t)64 * K;
    _Float16* lAh = As_h + t * 8;
    _Float16* lAl = As_l + t * 8;
    _Float16* lBh = Bs_h + t * 8;
    _Float16* lBl = Bs_l + t * 8;

    // fragment read offsets (elements): A row = wm*32 + (l&15) (+16 per mi); k0 = (l>>4)*8
    const int aoff = (wm * 32 + (l & 15)) * BK + (l >> 4) * 8;
    const int boff = (wn * 64 + (l & 15)) * BK + (l >> 4) * 8;

    f32x4 accM[2][4], accX[2][4];
#pragma unroll
    for (int mi = 0; mi < 2; ++mi)
#pragma unroll
        for (int ni = 0; ni < 4; ++ni) {
            accM[mi][ni] = (f32x4)(0.0f);
            accX[mi][ni] = (f32x4)(0.0f);
        }

    const int NT = K / BK;
    for (int kt = 0; kt < NT; ++kt) {
        const int ko = kt * BK;
        __syncthreads();                       // previous iter done reading LDS
        GLD16(ApH + ko, lAh);
        GLD16(ApL + ko, lAl);
        GLD16(BpH + ko, lBh);
        GLD16(BpH2 + ko, lBh + 2048);
        GLD16(BpL + ko, lBl);
        GLD16(BpL2 + ko, lBl + 2048);
        __syncthreads();                       // compiler drains vmcnt before barrier

        f16x8 fah[2], fal[2], fbh[4], fbl[4];
#pragma unroll
        for (int mi = 0; mi < 2; ++mi) {
            fah[mi] = *reinterpret_cast<const f16x8*>(As_h + aoff + mi * 16 * BK);
            fal[mi] = *reinterpret_cast<const f16x8*>(As_l + aoff + mi * 16 * BK);
        }
#pragma unroll
        for (int ni = 0; ni < 4; ++ni) {
            fbh[ni] = *reinterpret_cast<const f16x8*>(Bs_h + boff + ni * 16 * BK);
            fbl[ni] = *reinterpret_cast<const f16x8*>(Bs_l + boff + ni * 16 * BK);
        }
#pragma unroll
        for (int mi = 0; mi < 2; ++mi)
#pragma unroll
            for (int ni = 0; ni < 4; ++ni) {
                accM[mi][ni] = __builtin_amdgcn_mfma_f32_16x16x32_f16(fah[mi], fbh[ni], accM[mi][ni], 0, 0, 0);
                accX[mi][ni] = __builtin_amdgcn_mfma_f32_16x16x32_f16(fal[mi], fbh[ni], accX[mi][ni], 0, 0, 0);
                accX[mi][ni] = __builtin_amdgcn_mfma_f32_16x16x32_f16(fah[mi], fbl[ni], accX[mi][ni], 0, 0, 0);
            }
    }

    // epilogue
#pragma unroll
    for (int mi = 0; mi < 2; ++mi) {
#pragma unroll
        for (int ni = 0; ni < 4; ++ni) {
            const int row0 = bm + wm * 32 + mi * 16 + (l >> 4) * 4;
            const int col = bn + wn * 64 + ni * 16 + (l & 15);
            const float bb = bias[col];
#pragma unroll
            for (int r = 0; r < 4; ++r) {
                const float o = accM[mi][ni][r] + accX[mi][ni][r] * (1.0f / 2048.0f) + bb;
                const size_t idx = (size_t)(row0 + r) * N + col;
                if (EPI == 0) {
                    Co[idx] = o;
                } else if (EPI == 1) {
                    const float g = gelu_f(o);
                    const _Float16 hi = (_Float16)g;
                    Oh[idx] = hi;
                    Ol[idx] = (_Float16)((g - (float)hi) * 2048.0f);
                } else {
                    Co[idx] = o + resid[idx];
                }
            }
        }
    }
}

// ---------------- causal flash attention, fp32 ----------------
#define AQT 64
#define AKT 64
#define APAD 68

__global__ __launch_bounds__(128)
void attn_kernel(const float* __restrict__ qkv, float* __restrict__ y)
{
    __shared__ float Qs[AQT][APAD];
    __shared__ float KPs[AKT][APAD];
    __shared__ float Vs[AKT][APAD];

    const int t = threadIdx.x;
    const int q0 = blockIdx.x * AQT;
    const int bh = blockIdx.y;
    const int b = bh >> 4;
    const int h = bh & 15;

    const size_t base = (size_t)b * T_DIM * 3072 + (size_t)h * 64;

    const int lr = t >> 4;
    const int fcol = (t & 15) * 4;

#pragma unroll
    for (int i = 0; i < 8; ++i) {
        const int r = lr + i * 8;
        const float4 v = *reinterpret_cast<const float4*>(
            &qkv[base + (size_t)(q0 + r) * 3072 + fcol]);
        const float4 sv = make_float4(v.x * 0.125f, v.y * 0.125f, v.z * 0.125f, v.w * 0.125f);
        *reinterpret_cast<float4*>(&Qs[r][fcol]) = sv;
    }

    const int rm = (t >> 3) * 4;
    const int cn = (t & 7) * 8;

    float mrow[4], lrow[4], o[4][8];
#pragma unroll
    for (int i = 0; i < 4; ++i) {
        mrow[i] = -INFINITY; lrow[i] = 0.0f;
#pragma unroll
        for (int j = 0; j < 8; ++j) o[i][j] = 0.0f;
    }

    for (int k0 = 0; k0 <= q0; k0 += AKT) {
        __syncthreads();
#pragma unroll
        for (int i = 0; i < 8; ++i) {
            const int r = lr + i * 8;
            const size_t roff = base + (size_t)(k0 + r) * 3072;
            const float4 kv = *reinterpret_cast<const float4*>(&qkv[roff + 1024 + fcol]);
            const float4 vv = *reinterpret_cast<const float4*>(&qkv[roff + 2048 + fcol]);
            *reinterpret_cast<float4*>(&KPs[r][fcol]) = kv;
            *reinterpret_cast<float4*>(&Vs[r][fcol]) = vv;
        }
        __syncthreads();

        float s[4][8] = {};
#pragma unroll 2
        for (int dd = 0; dd < 64; dd += 4) {
            float4 a4[4], k4[8];
#pragma unroll
            for (int i = 0; i < 4; ++i)
                a4[i] = *reinterpret_cast<const float4*>(&Qs[rm + i][dd]);
#pragma unroll
            for (int j = 0; j < 8; ++j)
                k4[j] = *reinterpret_cast<const float4*>(&KPs[cn + j][dd]);
#pragma unroll
            for (int i = 0; i < 4; ++i)
#pragma unroll
                for (int j = 0; j < 8; ++j)
                    s[i][j] += a4[i].x * k4[j].x + a4[i].y * k4[j].y
                             + a4[i].z * k4[j].z + a4[i].w * k4[j].w;
        }

        if (k0 == q0) {
#pragma unroll
            for (int i = 0; i < 4; ++i)
#pragma unroll
                for (int j = 0; j < 8; ++j)
                    if (cn + j > rm + i) s[i][j] = -INFINITY;
        }

#pragma unroll
        for (int i = 0; i < 4; ++i) {
            float pm = s[i][0];
#pragma unroll
            for (int j = 1; j < 8; ++j) pm = fmaxf(pm, s[i][j]);
            pm = fmaxf(pm, __shfl_xor(pm, 1));
            pm = fmaxf(pm, __shfl_xor(pm, 2));
            pm = fmaxf(pm, __shfl_xor(pm, 4));
            const float mnew = fmaxf(mrow[i], pm);
            float rs = 0.0f;
#pragma unroll
            for (int j = 0; j < 8; ++j) {
                s[i][j] = __expf(s[i][j] - mnew);
                rs += s[i][j];
            }
            rs += __shfl_xor(rs, 1);
            rs += __shfl_xor(rs, 2);
            rs += __shfl_xor(rs, 4);
            const float sc = __expf(mrow[i] - mnew);
            lrow[i] = lrow[i] * sc + rs;
            mrow[i] = mnew;
#pragma unroll
            for (int j = 0; j < 8; ++j) o[i][j] *= sc;
        }

        __syncthreads();
#pragma unroll
        for (int j = 0; j < 8; ++j) {
            const float4 pv = make_float4(s[0][j], s[1][j], s[2][j], s[3][j]);
            *reinterpret_cast<float4*>(&KPs[cn + j][rm]) = pv;
        }
        __syncthreads();

        for (int kc = 0; kc < AKT; kc += 4) {
            float4 p4[4], v4a[4], v4b[4];
#pragma unroll
            for (int c = 0; c < 4; ++c) {
                p4[c]  = *reinterpret_cast<const float4*>(&KPs[kc + c][rm]);
                v4a[c] = *reinterpret_cast<const float4*>(&Vs[kc + c][cn]);
                v4b[c] = *reinterpret_cast<const float4*>(&Vs[kc + c][cn + 4]);
            }
#pragma unroll
            for (int c = 0; c < 4; ++c) {
                const float pr[4] = {p4[c].x, p4[c].y, p4[c].z, p4[c].w};
                const float vr[8] = {v4a[c].x, v4a[c].y, v4a[c].z, v4a[c].w,
                                     v4b[c].x, v4b[c].y, v4b[c].z, v4b[c].w};
#pragma unroll
                for (int i = 0; i < 4; ++i)
#pragma unroll
                    for (int j = 0; j < 8; ++j)
                        o[i][j] += pr[i] * vr[j];
            }
        }
    }

#pragma unroll
    for (int i = 0; i < 4; ++i) {
        const float inv = 1.0f / lrow[i];
        const size_t off = ((size_t)b * T_DIM + q0 + rm + i) * C_DIM + (size_t)h * 64 + cn;
        const float4 o0 = make_float4(o[i][0] * inv, o[i][1] * inv, o[i][2] * inv, o[i][3] * inv);
        const float4 o1 = make_float4(o[i][4] * inv, o[i][5] * inv, o[i][6] * inv, o[i][7] * inv);
        *reinterpret_cast<float4*>(&y[off]) = o0;
        *reinterpret_cast<float4*>(&y[off + 4]) = o1;
    }
}

// ---------------- launch ----------------
#define MB (size_t)(1 << 20)

extern "C" void kernel_launch(void* const* d_in, const int* in_sizes, int n_in,
                              void* d_out, int out_size, void* d_ws, size_t ws_size,
                              hipStream_t stream)
{
    const float* x      = (const float*)d_in[0];
    const float* ln1_g  = (const float*)d_in[1];
    const float* ln1_b  = (const float*)d_in[2];
    const float* W_attn = (const float*)d_in[3];
    const float* b_attn = (const float*)d_in[4];
    const float* ln2_g  = (const float*)d_in[5];
    const float* ln2_b  = (const float*)d_in[6];
    const float* W_fc   = (const float*)d_in[7];
    const float* b_fc   = (const float*)d_in[8];
    const float* W_proj = (const float*)d_in[9];
    const float* b_proj = (const float*)d_in[10];
    float* out = (float*)d_out;

    // workspace layout (140 MB):
    //  [0,48)    qkv fp32         -> after attention reused: mh [0,32) + ml [32,64) fp16
    //  [48,64)   y fp32 (attn out; dead after LN2)
    //  [64,80)   x2 fp32
    //  [80,96)   hh/hl fp16 (LN1 out, reused for LN2 out)
    //  [96,140)  transposed split weights
    char* ws = (char*)d_ws;
    float*    qkv  = (float*)(ws);
    float*    y    = (float*)(ws + 48 * MB);
    float*    x2   = (float*)(ws + 64 * MB);
    _Float16* hh   = (_Float16*)(ws + 80 * MB);
    _Float16* hl   = (_Float16*)(ws + 88 * MB);
    _Float16* mh   = (_Float16*)(ws);            // aliases qkv (dead)
    _Float16* ml   = (_Float16*)(ws + 32 * MB);  // aliases qkv+y (dead)
    _Float16* WAth = (_Float16*)(ws + 96 * MB);
    _Float16* WAtl = (_Float16*)(ws + 102 * MB);
    _Float16* WFth = (_Float16*)(ws + 108 * MB);
    _Float16* WFtl = (_Float16*)(ws + 116 * MB);
    _Float16* WPth = (_Float16*)(ws + 124 * MB);
    _Float16* WPtl = (_Float16*)(ws + 132 * MB);

    // 0) weight transpose+split
    wsplit_kernel<<<dim3(3072 / 32, 1024 / 32), dim3(256), 0, stream>>>(W_attn, WAth, WAtl, 1024, 3072);
    wsplit_kernel<<<dim3(4096 / 32, 1024 / 32), dim3(256), 0, stream>>>(W_fc, WFth, WFtl, 1024, 4096);
    wsplit_kernel<<<dim3(1024 / 32, 4096 / 32), dim3(256), 0, stream>>>(W_proj, WPth, WPtl, 4096, 1024);
    // 1) hh/hl = split(LN1(x))
    ln_split_kernel<<<dim3(M_TOK), dim3(256), 0, stream>>>(x, nullptr, ln1_g, ln1_b, hh, hl, nullptr);
    // 2) qkv = h @ W_attn + b_attn   (fp16x2 MFMA)
    gemm16_kernel<0><<<dim3(3072 / BTN, M_TOK / BTM), dim3(256), 0, stream>>>(
        hh, hl, WAth, WAtl, b_attn, nullptr, qkv, nullptr, nullptr, M_TOK, 3072, 1024);
    // 3) y = causal_attention(qkv)
    attn_kernel<<<dim3(T_DIM / AQT, B_DIM * H_NUM), dim3(128), 0, stream>>>(qkv, y);
    // 4) x2 = x + y ; hh/hl = split(LN2(x2))
    ln_split_kernel<<<dim3(M_TOK), dim3(256), 0, stream>>>(x, y, ln2_g, ln2_b, hh, hl, x2);
    // 5) mh/ml = split(gelu(h2 @ W_fc + b_fc))
    gemm16_kernel<1><<<dim3(4096 / BTN, M_TOK / BTM), dim3(256), 0, stream>>>(
        hh, hl, WFth, WFtl, b_fc, nullptr, nullptr, mh, ml, M_TOK, 4096, 1024);
    // 6) out = m @ W_proj + b_proj + x2
    gemm16_kernel<2><<<dim3(1024 / BTN, M_TOK / BTM), dim3(256), 0, stream>>>(
        mh, ml, WPth, WPtl, b_proj, x2, out, nullptr, nullptr, M_TOK, 1024, 4096);
}